// Round 4
// baseline (239.588 us; speedup 1.0000x reference)
//
#include <hip/hip_runtime.h>

// Problem constants (from reference setup_inputs)
constexpr int B = 4, D = 32, C = 3, H = 256, W = 384;
constexpr int HW = H * W;            // 98304
constexpr int HW2 = HW / 2;          // 49152 float2-groups per plane-image
constexpr int PIX2 = B * HW2;        // 196608 threads total (2 px each)

__global__ __launch_bounds__(256)
void alpha_comp_kernel(const float* __restrict__ src,
                       const float* __restrict__ alpha,
                       float* __restrict__ out)
{
    const int tid = blockIdx.x * blockDim.x + threadIdx.x;
    if (tid >= PIX2) return;

    const int b   = tid / HW2;
    const int hw2 = tid - b * HW2;   // float2 index within the H*W image

    const float2* __restrict__ ap =
        reinterpret_cast<const float2*>(alpha) + (size_t)b * D * HW2 + hw2;
    const float2* __restrict__ sp =
        reinterpret_cast<const float2*>(src) + (size_t)b * D * C * HW2 + hw2;

    float res[2]    = {1.f, 1.f};    // exclusive cumprod of (1-a)
    float vsum[2]   = {0.f, 0.f};    // sum of visibility
    float acc[3][2] = {};            // unnormalized output accum

    #pragma unroll 8
    for (int d = 0; d < D; ++d) {
        const float2 a  = ap[(size_t)d * HW2];
        const float2 s0 = sp[((size_t)d * C + 0) * HW2];
        const float2 s1 = sp[((size_t)d * C + 1) * HW2];
        const float2 s2 = sp[((size_t)d * C + 2) * HW2];

        const float av[2]  = {a.x, a.y};
        const float s0v[2] = {s0.x, s0.y};
        const float s1v[2] = {s1.x, s1.y};
        const float s2v[2] = {s2.x, s2.y};

        #pragma unroll
        for (int k = 0; k < 2; ++k) {
            const float vis = res[k] * av[k];
            vsum[k]  += vis;
            acc[0][k] = fmaf(s0v[k], vis, acc[0][k]);
            acc[1][k] = fmaf(s1v[k], vis, acc[1][k]);
            acc[2][k] = fmaf(s2v[k], vis, acc[2][k]);
            res[k]   *= (1.f - av[k]);
        }
    }

    float2* __restrict__ op =
        reinterpret_cast<float2*>(out) + (size_t)b * C * HW2 + hw2;

    float inv[2];
    #pragma unroll
    for (int k = 0; k < 2; ++k)
        inv[k] = 1.f / fmaxf(vsum[k], 1e-7f);

    #pragma unroll
    for (int c = 0; c < C; ++c) {
        float2 o;
        o.x = acc[c][0] * inv[0];
        o.y = acc[c][1] * inv[1];
        op[(size_t)c * HW2] = o;
    }
}

extern "C" void kernel_launch(void* const* d_in, const int* in_sizes, int n_in,
                              void* d_out, int out_size, void* d_ws, size_t ws_size,
                              hipStream_t stream)
{
    const float* src   = (const float*)d_in[0];   // [B, D, C, H, W]
    const float* alpha = (const float*)d_in[1];   // [B, D, 1, H, W]
    float* out = (float*)d_out;                   // [B, C, H, W]

    const int threads = 256;
    const int blocks  = (PIX2 + threads - 1) / threads;  // 768
    alpha_comp_kernel<<<blocks, threads, 0, stream>>>(src, alpha, out);
}